// Round 4
// baseline (1183.761 us; speedup 1.0000x reference)
//
#include <hip/hip_runtime.h>
#include <hip/hip_bf16.h>

typedef unsigned short ushort;
typedef short bf16x8 __attribute__((ext_vector_type(8)));
typedef float f32x4 __attribute__((ext_vector_type(4)));

#define NB 8
#define SS 2048
#define DD 768
#define DKV 214
#define DKP 224
#define WROWS 256

__device__ __forceinline__ float bf2f(ushort u) {
  union { unsigned int i; float f; } v; v.i = ((unsigned int)u) << 16; return v.f;
}
__device__ __forceinline__ ushort f2bf(float f) {
  union { float f; unsigned int i; } v; v.f = f;
  unsigned int x = v.i;
  return (ushort)((x + 0x7fffu + ((x >> 16) & 1u)) >> 16);
}
__device__ __forceinline__ bf16x8 cvt8(const float* p) {
  f32x4 a = *(const f32x4*)p;
  f32x4 b = *(const f32x4*)(p + 4);
  bf16x8 r;
#pragma unroll
  for (int j = 0; j < 4; ++j) { r[j] = (short)f2bf(a[j]); r[j + 4] = (short)f2bf(b[j]); }
  return r;
}
__device__ __forceinline__ void split8(const float* p, bf16x8& h, bf16x8& l) {
  f32x4 a = *(const f32x4*)p;
  f32x4 b = *(const f32x4*)(p + 4);
#pragma unroll
  for (int j = 0; j < 4; ++j) {
    ushort h0 = f2bf(a[j]); h[j]     = (short)h0; l[j]     = (short)f2bf(a[j] - bf2f(h0));
    ushort h1 = f2bf(b[j]); h[j + 4] = (short)h1; l[j + 4] = (short)f2bf(b[j] - bf2f(h1));
  }
}

// ---- weight prep: split Wq,Wk into padded [WROWS][768] hi/lo; cvt Wv to bf16 ----
__global__ __launch_bounds__(256)
void prep_w(const float* __restrict__ Wq, const float* __restrict__ Wk,
            const float* __restrict__ Wv,
            ushort* __restrict__ Wqh, ushort* __restrict__ Wql,
            ushort* __restrict__ Wkh, ushort* __restrict__ Wkl,
            ushort* __restrict__ Wvb)
{
  const int NW = WROWS * DD;          // 196608
  const int NV = DD * DD;             // 589824
  for (int i = blockIdx.x * 256 + threadIdx.x; i < 2 * NW + NV; i += gridDim.x * 256) {
    if (i < NW) {
      int r = i / DD;
      float v = (r < DKV) ? Wq[i] : 0.f;
      ushort h = f2bf(v);
      Wqh[i] = h; Wql[i] = f2bf(v - bf2f(h));
    } else if (i < 2 * NW) {
      int j = i - NW;
      int r = j / DD;
      float v = (r < DKV) ? Wk[j] : 0.f;
      ushort h = f2bf(v);
      Wkh[j] = h; Wkl[j] = f2bf(v - bf2f(h));
    } else {
      int j = i - 2 * NW;
      Wvb[j] = f2bf(Wv[j]);
    }
  }
}

// ---- Q/K projection: A f32 (in-loop split), W pre-split. C = hi/lo bf16 pair ----
__global__ __launch_bounds__(256)
void gemm_qk(const float* __restrict__ A, const ushort* __restrict__ Bh,
             const ushort* __restrict__ Bl, const float* __restrict__ bias,
             ushort* __restrict__ Ch, ushort* __restrict__ Cl)
{
  const int m0 = blockIdx.x * 64;
  const int n0 = blockIdx.y * 64;
  const int tid = threadIdx.x;
  const int w  = tid >> 6;
  const int l  = tid & 63;
  const int lr = l & 15;
  const int lh = l >> 4;

  const f32x4 fzero = {0.f, 0.f, 0.f, 0.f};
  f32x4 acc[4];
#pragma unroll
  for (int nt = 0; nt < 4; ++nt) acc[nt] = fzero;

  const float* arow = A + (size_t)(m0 + w * 16 + lr) * DD + lh * 8;
  const ushort* bh[4]; const ushort* bl[4];
#pragma unroll
  for (int nt = 0; nt < 4; ++nt) {
    int n = n0 + nt * 16 + lr;
    bh[nt] = Bh + (size_t)n * DD + lh * 8;
    bl[nt] = Bl + (size_t)n * DD + lh * 8;
  }

  for (int k = 0; k < DD; k += 32) {
    bf16x8 ah, al; split8(arow + k, ah, al);
#pragma unroll
    for (int nt = 0; nt < 4; ++nt) {
      bf16x8 wh = *(const bf16x8*)(bh[nt] + k);
      bf16x8 wl = *(const bf16x8*)(bl[nt] + k);
      acc[nt] = __builtin_amdgcn_mfma_f32_16x16x32_bf16(ah, wh, acc[nt], 0, 0, 0);
      acc[nt] = __builtin_amdgcn_mfma_f32_16x16x32_bf16(ah, wl, acc[nt], 0, 0, 0);
      acc[nt] = __builtin_amdgcn_mfma_f32_16x16x32_bf16(al, wh, acc[nt], 0, 0, 0);
    }
  }

#pragma unroll
  for (int nt = 0; nt < 4; ++nt) {
    int n = n0 + nt * 16 + lr;
    if (n >= DKP) continue;
    float bv = (n < DKV) ? bias[n] : 0.f;
#pragma unroll
    for (int r = 0; r < 4; ++r) {
      int m = m0 + w * 16 + lh * 4 + r;
      float val = (n < DKV) ? (acc[nt][r] + bv) : 0.f;
      ushort h = f2bf(val);
      Ch[(size_t)m * DKP + n] = h;
      Cl[(size_t)m * DKP + n] = f2bf(val - bf2f(h));
    }
  }
}

// ---- V projection: A f32 (in-loop cvt), W pre-cvt bf16; out Vt[b][d][s] bf16 ----
__global__ __launch_bounds__(256)
void gemm_v(const float* __restrict__ A, const ushort* __restrict__ Bw,
            const float* __restrict__ bias, ushort* __restrict__ Vt)
{
  const int m0 = blockIdx.x * 64;
  const int n0 = blockIdx.y * 64;
  const int tid = threadIdx.x;
  const int w  = tid >> 6;
  const int l  = tid & 63;
  const int lr = l & 15;
  const int lh = l >> 4;

  const f32x4 fzero = {0.f, 0.f, 0.f, 0.f};
  f32x4 acc[4];
#pragma unroll
  for (int nt = 0; nt < 4; ++nt) acc[nt] = fzero;

  const float* arow = A + (size_t)(m0 + w * 16 + lr) * DD + lh * 8;
  const ushort* brow[4];
#pragma unroll
  for (int nt = 0; nt < 4; ++nt)
    brow[nt] = Bw + (size_t)(n0 + nt * 16 + lr) * DD + lh * 8;

  for (int k = 0; k < DD; k += 32) {
    bf16x8 af = cvt8(arow + k);
#pragma unroll
    for (int nt = 0; nt < 4; ++nt) {
      bf16x8 bfr = *(const bf16x8*)(brow[nt] + k);
      acc[nt] = __builtin_amdgcn_mfma_f32_16x16x32_bf16(af, bfr, acc[nt], 0, 0, 0);
    }
  }

  __shared__ ushort lt[64][72];
#pragma unroll
  for (int nt = 0; nt < 4; ++nt) {
    int nl = nt * 16 + lr;
    float bv = bias[n0 + nl];
#pragma unroll
    for (int r = 0; r < 4; ++r)
      lt[nl][w * 16 + lh * 4 + r] = f2bf(acc[nt][r] + bv);
  }
  __syncthreads();
  const int bb = m0 >> 11;
  const int s0 = m0 & 2047;
  for (int i = tid; i < 64 * 64; i += 256) {
    int nn = i >> 6, mm = i & 63;
    Vt[(size_t)bb * (DD * SS) + (size_t)(n0 + nn) * SS + (s0 + mm)] = lt[nn][mm];
  }
}

// ---- fused attention, latency-pipelined ----
// Block = batch b, 32 q-rows. 8 waves. t-tiles of 64, online softmax.
// Wave w: S quadrant rows (w&1)*16.., cols (w>>1)*16..; PV d-slice w*96..
// Raw barriers (lgkm-only) keep global prefetches in flight across phases.
__global__ __launch_bounds__(512, 4)
void attn_fused(const ushort* __restrict__ Qh, const ushort* __restrict__ Ql,
                const ushort* __restrict__ Kh, const ushort* __restrict__ Kl,
                const ushort* __restrict__ Vt, const float* __restrict__ isc,
                const float* __restrict__ dmask, float* __restrict__ out)
{
  const int bb = blockIdx.x >> 6;
  const int q0 = (blockIdx.x & 63) << 5;
  const int tid = threadIdx.x;
  const int w  = tid >> 6;
  const int l  = tid & 63;
  const int lr = l & 15;
  const int lh = l >> 4;
  const int rh = w & 1;
  const int cq = w >> 1;

  __shared__ __align__(16) ushort Qlh[32][232];
  __shared__ __align__(16) ushort Qll[32][232];
  __shared__ __align__(16) ushort Plds[2][2048];  // [32][64] bf16, XOR-swizzled, dbuf
  __shared__ float part_max[2][4][32];
  __shared__ float part_sum[2][4][32];
  __shared__ float alpha_l[2][32];
  __shared__ float rcpZ[32];

  {
    const size_t qoff = (size_t)(bb * SS + q0) * DKP;
    for (int i = tid; i < 32 * 28; i += 512) {
      int r = i / 28, c = i % 28;
      *(bf16x8*)(&Qlh[r][c * 8]) = *(const bf16x8*)(Qh + qoff + r * DKP + c * 8);
      *(bf16x8*)(&Qll[r][c * 8]) = *(const bf16x8*)(Ql + qoff + r * DKP + c * 8);
    }
  }
  __syncthreads();

  const f32x4 fzero = {0.f, 0.f, 0.f, 0.f};
  float m_run[4], Z_run[4];
#pragma unroll
  for (int r = 0; r < 4; ++r) { m_run[r] = -1e30f; Z_run[r] = 0.f; }
  f32x4 Oacc[2][6];
#pragma unroll
  for (int mt = 0; mt < 2; ++mt)
#pragma unroll
    for (int dt = 0; dt < 6; ++dt) Oacc[mt][dt] = fzero;

  const int qrow_w = rh * 16 + lh * 4;

  // incremental stream pointers
  const ushort* krh = Kh + (size_t)(bb * SS + cq * 16 + lr) * DKP + lh * 8;
  const ushort* krl = Kl + (size_t)(bb * SS + cq * 16 + lr) * DKP + lh * 8;
  const float*  dmp = dmask + (size_t)bb * SS * SS + (size_t)(q0 + qrow_w) * SS + cq * 16 + lr;
  const float*  icp = isc + (size_t)(q0 + qrow_w) * SS + cq * 16 + lr;
  const ushort* vcr = Vt + (size_t)bb * (DD * SS) + (size_t)(w * 96 + lr) * SS + lh * 8;

  for (int it = 0; it < SS / 64; ++it) {
    const int b = it & 1;
    // ---- issue current-tile scalar streams (dropout mask: cold HBM; hide under QK) ----
    float dmv[4], icv[4];
#pragma unroll
    for (int r = 0; r < 4; ++r) { dmv[r] = dmp[(size_t)r * SS]; icv[r] = icp[(size_t)r * SS]; }
    // ---- K tile into registers (14 loads, batched) ----
    bf16x8 kh[7], kl[7];
#pragma unroll
    for (int k = 0; k < 7; ++k) {
      kh[k] = *(const bf16x8*)(krh + k * 32);
      kl[k] = *(const bf16x8*)(krl + k * 32);
    }
    // ---- QK: 3 independent accumulator chains ----
    f32x4 a0 = fzero, a1 = fzero, a2 = fzero;
    __builtin_amdgcn_s_setprio(1);
#pragma unroll
    for (int k = 0; k < 7; ++k) {
      bf16x8 ah = *(const bf16x8*)(&Qlh[rh * 16 + lr][k * 32 + lh * 8]);
      bf16x8 al = *(const bf16x8*)(&Qll[rh * 16 + lr][k * 32 + lh * 8]);
      a0 = __builtin_amdgcn_mfma_f32_16x16x32_bf16(ah, kh[k], a0, 0, 0, 0);
      a1 = __builtin_amdgcn_mfma_f32_16x16x32_bf16(ah, kl[k], a1, 0, 0, 0);
      a2 = __builtin_amdgcn_mfma_f32_16x16x32_bf16(al, kh[k], a2, 0, 0, 0);
    }
    __builtin_amdgcn_s_setprio(0);
    f32x4 sacc = (a0 + a1) + a2;
    float sv[4];
#pragma unroll
    for (int r = 0; r < 4; ++r) sv[r] = sacc[r] * __builtin_amdgcn_rcpf(icv[r]);
    // ---- row max over 16-lane groups ----
    float mx[4];
#pragma unroll
    for (int r = 0; r < 4; ++r) mx[r] = sv[r];
#pragma unroll
    for (int off = 1; off < 16; off <<= 1) {
#pragma unroll
      for (int r = 0; r < 4; ++r) mx[r] = fmaxf(mx[r], __shfl_xor(mx[r], off));
    }
    if (lr == 0) {
#pragma unroll
      for (int r = 0; r < 4; ++r) part_max[b][cq][qrow_w + r] = mx[r];
    }
    // ---- issue V batch A (dt 0..2) during softmax ----
    bf16x8 vfa[6];
#pragma unroll
    for (int dt = 0; dt < 3; ++dt) {
#pragma unroll
      for (int ks = 0; ks < 2; ++ks)
        vfa[dt * 2 + ks] = *(const bf16x8*)(vcr + (size_t)dt * 16 * SS + ks * 32);
    }
    asm volatile("s_waitcnt lgkmcnt(0)" ::: "memory");
    __builtin_amdgcn_s_barrier();                     // barrier A (no vmcnt drain)
    // ---- combine col-quarters, online update ----
    float alpha[4], e[4], zl[4];
#pragma unroll
    for (int r = 0; r < 4; ++r) {
      int row = qrow_w + r;
      float mt4 = fmaxf(fmaxf(part_max[b][0][row], part_max[b][1][row]),
                        fmaxf(part_max[b][2][row], part_max[b][3][row]));
      float mnew = fmaxf(m_run[r], mt4);
      alpha[r] = __expf(m_run[r] - mnew);
      m_run[r] = mnew;
      e[r]  = __expf(sv[r] - mnew);
      zl[r] = e[r];
    }
#pragma unroll
    for (int off = 1; off < 16; off <<= 1) {
#pragma unroll
      for (int r = 0; r < 4; ++r) zl[r] += __shfl_xor(zl[r], off);
    }
    if (lr == 0) {
#pragma unroll
      for (int r = 0; r < 4; ++r) part_sum[b][cq][qrow_w + r] = zl[r];
      if (cq == 0) {
#pragma unroll
        for (int r = 0; r < 4; ++r) alpha_l[b][qrow_w + r] = alpha[r];
      }
    }
    // ---- P = e * dropout (post-normalization mask; Z stays unmasked) ----
#pragma unroll
    for (int r = 0; r < 4; ++r) {
      int row = qrow_w + r;
      int col = cq * 16 + lr;
      unsigned off = (unsigned)(row * 128 + col * 2) ^ (((unsigned)row & 7u) << 4);
      *(ushort*)((char*)&Plds[b][0] + off) = f2bf(e[r] * dmv[r]);
    }
    asm volatile("s_waitcnt lgkmcnt(0)" ::: "memory");
    __builtin_amdgcn_s_barrier();                     // barrier B
    // ---- Z update + O rescale ----
#pragma unroll
    for (int r = 0; r < 4; ++r) {
      int row = qrow_w + r;
      Z_run[r] = Z_run[r] * alpha[r] +
                 part_sum[b][0][row] + part_sum[b][1][row] +
                 part_sum[b][2][row] + part_sum[b][3][row];
    }
    float oal[2][4]; int need = 0;
#pragma unroll
    for (int mt = 0; mt < 2; ++mt) {
#pragma unroll
      for (int r = 0; r < 4; ++r) {
        float a = alpha_l[b][mt * 16 + lh * 4 + r];
        oal[mt][r] = a;
        need |= (a != 1.f);
      }
    }
    if (__any(need)) {
#pragma unroll
      for (int mt = 0; mt < 2; ++mt)
#pragma unroll
        for (int dt = 0; dt < 6; ++dt)
#pragma unroll
          for (int r = 0; r < 4; ++r) Oacc[mt][dt][r] *= oal[mt][r];
    }
    // ---- PV ----
    bf16x8 pf[2][2];
#pragma unroll
    for (int mt = 0; mt < 2; ++mt) {
#pragma unroll
      for (int ks = 0; ks < 2; ++ks) {
        int row = mt * 16 + lr;
        unsigned off = (unsigned)(row * 128 + ks * 64 + lh * 16) ^ (((unsigned)row & 7u) << 4);
        pf[mt][ks] = *(const bf16x8*)((char*)&Plds[b][0] + off);
      }
    }
    // issue V batch B (dt 3..5) before consuming batch A
    bf16x8 vfb[6];
#pragma unroll
    for (int dt = 0; dt < 3; ++dt) {
#pragma unroll
      for (int ks = 0; ks < 2; ++ks)
        vfb[dt * 2 + ks] = *(const bf16x8*)(vcr + (size_t)(dt + 3) * 16 * SS + ks * 32);
    }
    __builtin_amdgcn_s_setprio(1);
#pragma unroll
    for (int dt = 0; dt < 3; ++dt) {
#pragma unroll
      for (int ks = 0; ks < 2; ++ks) {
        Oacc[0][dt] = __builtin_amdgcn_mfma_f32_16x16x32_bf16(pf[0][ks], vfa[dt * 2 + ks], Oacc[0][dt], 0, 0, 0);
        Oacc[1][dt] = __builtin_amdgcn_mfma_f32_16x16x32_bf16(pf[1][ks], vfa[dt * 2 + ks], Oacc[1][dt], 0, 0, 0);
      }
    }
#pragma unroll
    for (int dt = 0; dt < 3; ++dt) {
#pragma unroll
      for (int ks = 0; ks < 2; ++ks) {
        Oacc[0][dt + 3] = __builtin_amdgcn_mfma_f32_16x16x32_bf16(pf[0][ks], vfb[dt * 2 + ks], Oacc[0][dt + 3], 0, 0, 0);
        Oacc[1][dt + 3] = __builtin_amdgcn_mfma_f32_16x16x32_bf16(pf[1][ks], vfb[dt * 2 + ks], Oacc[1][dt + 3], 0, 0, 0);
      }
    }
    __builtin_amdgcn_s_setprio(0);
    // advance streams (no trailing barrier: Plds/part arrays are double-buffered)
    krh += 64 * DKP; krl += 64 * DKP; dmp += 64; icp += 64; vcr += 64;
  }

  if (w < 2 && lr == 0) {
#pragma unroll
    for (int r = 0; r < 4; ++r) rcpZ[qrow_w + r] = 1.0f / Z_run[r];
  }
  __syncthreads();

  float* obase = out + (size_t)(bb * SS + q0) * DD + w * 96;
#pragma unroll
  for (int mt = 0; mt < 2; ++mt) {
#pragma unroll
    for (int dt = 0; dt < 6; ++dt) {
#pragma unroll
      for (int r = 0; r < 4; ++r) {
        int row = mt * 16 + lh * 4 + r;
        obase[(size_t)row * DD + dt * 16 + lr] = Oacc[mt][dt][r] * rcpZ[row];
      }
    }
  }
}

extern "C" void kernel_launch(void* const* d_in, const int* in_sizes, int n_in,
                              void* d_out, int out_size, void* d_ws, size_t ws_size,
                              hipStream_t stream) {
  const float* x1  = (const float*)d_in[0];
  const float* x2  = (const float*)d_in[1];
  const float* x3  = (const float*)d_in[2];
  const float* Wq  = (const float*)d_in[3];
  const float* bq  = (const float*)d_in[4];
  const float* Wk  = (const float*)d_in[5];
  const float* bk  = (const float*)d_in[6];
  const float* Wv  = (const float*)d_in[7];
  const float* bv  = (const float*)d_in[8];
  const float* isc = (const float*)d_in[9];
  const float* dmk = (const float*)d_in[10];
  float* out = (float*)d_out;

  const size_t QK = (size_t)16384 * DKP;
  const size_t WN = (size_t)WROWS * DD;
  ushort* Qh  = (ushort*)d_ws;
  ushort* Ql  = Qh + QK;
  ushort* Kh  = Ql + QK;
  ushort* Kl  = Kh + QK;
  ushort* Vt  = Kl + QK;                       // [8][768][2048]
  ushort* Wqh = Vt + (size_t)NB * DD * SS;
  ushort* Wql = Wqh + WN;
  ushort* Wkh = Wql + WN;
  ushort* Wkl = Wkh + WN;
  ushort* Wvb = Wkl + WN;                      // [768][768]

  dim3 blk(256);
  prep_w<<<dim3(512), blk, 0, stream>>>(Wq, Wk, Wv, Wqh, Wql, Wkh, Wkl, Wvb);
  gemm_qk<<<dim3(256, 4),  blk, 0, stream>>>(x1, Wqh, Wql, bq, Qh, Ql);
  gemm_qk<<<dim3(256, 4),  blk, 0, stream>>>(x2, Wkh, Wkl, bk, Kh, Kl);
  gemm_v <<<dim3(256, 12), blk, 0, stream>>>(x3, Wvb, bv, Vt);
  attn_fused<<<dim3(512), dim3(512), 0, stream>>>(Qh, Ql, Kh, Kl, Vt, isc, dmk, out);
}

// Round 5
// 823.102 us; speedup vs baseline: 1.4382x; 1.4382x over previous
//
#include <hip/hip_runtime.h>
#include <hip/hip_bf16.h>

typedef unsigned short ushort;
typedef short bf16x8 __attribute__((ext_vector_type(8)));
typedef float f32x4 __attribute__((ext_vector_type(4)));

#define NB 8
#define SS 2048
#define DD 768
#define DKV 214
#define DKP 224
#define WROWS 256

__device__ __forceinline__ float bf2f(ushort u) {
  union { unsigned int i; float f; } v; v.i = ((unsigned int)u) << 16; return v.f;
}
__device__ __forceinline__ ushort f2bf(float f) {
  union { float f; unsigned int i; } v; v.f = f;
  unsigned int x = v.i;
  return (ushort)((x + 0x7fffu + ((x >> 16) & 1u)) >> 16);
}
__device__ __forceinline__ bf16x8 cvt8(const float* p) {
  f32x4 a = *(const f32x4*)p;
  f32x4 b = *(const f32x4*)(p + 4);
  bf16x8 r;
#pragma unroll
  for (int j = 0; j < 4; ++j) { r[j] = (short)f2bf(a[j]); r[j + 4] = (short)f2bf(b[j]); }
  return r;
}
__device__ __forceinline__ void split8(const float* p, bf16x8& h, bf16x8& l) {
  f32x4 a = *(const f32x4*)p;
  f32x4 b = *(const f32x4*)(p + 4);
#pragma unroll
  for (int j = 0; j < 4; ++j) {
    ushort h0 = f2bf(a[j]); h[j]     = (short)h0; l[j]     = (short)f2bf(a[j] - bf2f(h0));
    ushort h1 = f2bf(b[j]); h[j + 4] = (short)h1; l[j + 4] = (short)f2bf(b[j] - bf2f(h1));
  }
}

// ---- weight prep: split Wq,Wk into padded [WROWS][768] hi/lo; cvt Wv to bf16 ----
__global__ __launch_bounds__(256)
void prep_w(const float* __restrict__ Wq, const float* __restrict__ Wk,
            const float* __restrict__ Wv,
            ushort* __restrict__ Wqh, ushort* __restrict__ Wql,
            ushort* __restrict__ Wkh, ushort* __restrict__ Wkl,
            ushort* __restrict__ Wvb)
{
  const int NW = WROWS * DD;
  const int NV = DD * DD;
  for (int i = blockIdx.x * 256 + threadIdx.x; i < 2 * NW + NV; i += gridDim.x * 256) {
    if (i < NW) {
      int r = i / DD;
      float v = (r < DKV) ? Wq[i] : 0.f;
      ushort h = f2bf(v);
      Wqh[i] = h; Wql[i] = f2bf(v - bf2f(h));
    } else if (i < 2 * NW) {
      int j = i - NW;
      int r = j / DD;
      float v = (r < DKV) ? Wk[j] : 0.f;
      ushort h = f2bf(v);
      Wkh[j] = h; Wkl[j] = f2bf(v - bf2f(h));
    } else {
      int j = i - 2 * NW;
      Wvb[j] = f2bf(Wv[j]);
    }
  }
}

// ---- Q/K projection: 64m x 224n per block (n-grid=1 -> x read ONCE).
// A f32 (in-loop split), W pre-split. Out = hi/lo bf16 pair.
__global__ __launch_bounds__(256, 4)
void gemm_qk(const float* __restrict__ A, const ushort* __restrict__ Bh,
             const ushort* __restrict__ Bl, const float* __restrict__ bias,
             ushort* __restrict__ Ch, ushort* __restrict__ Cl)
{
  const int m0 = blockIdx.x * 64;
  const int tid = threadIdx.x;
  const int w  = tid >> 6;
  const int l  = tid & 63;
  const int lr = l & 15;
  const int lh = l >> 4;

  const f32x4 fzero = {0.f, 0.f, 0.f, 0.f};
  f32x4 acc[14];
#pragma unroll
  for (int nt = 0; nt < 14; ++nt) acc[nt] = fzero;

  const float* arow = A + (size_t)(m0 + w * 16 + lr) * DD + lh * 8;
  const ushort* bh0 = Bh + (size_t)lr * DD + lh * 8;
  const ushort* bl0 = Bl + (size_t)lr * DD + lh * 8;

  for (int k = 0; k < DD; k += 32) {
    bf16x8 ah, al; split8(arow + k, ah, al);
#pragma unroll
    for (int nt = 0; nt < 14; ++nt) {
      bf16x8 wh = *(const bf16x8*)(bh0 + (size_t)nt * 16 * DD + k);
      bf16x8 wl = *(const bf16x8*)(bl0 + (size_t)nt * 16 * DD + k);
      acc[nt] = __builtin_amdgcn_mfma_f32_16x16x32_bf16(ah, wh, acc[nt], 0, 0, 0);
      acc[nt] = __builtin_amdgcn_mfma_f32_16x16x32_bf16(ah, wl, acc[nt], 0, 0, 0);
      acc[nt] = __builtin_amdgcn_mfma_f32_16x16x32_bf16(al, wh, acc[nt], 0, 0, 0);
    }
  }

#pragma unroll
  for (int nt = 0; nt < 14; ++nt) {
    int n = nt * 16 + lr;
    float bv = (n < DKV) ? bias[n] : 0.f;
#pragma unroll
    for (int r = 0; r < 4; ++r) {
      int m = m0 + w * 16 + lh * 4 + r;
      float val = (n < DKV) ? (acc[nt][r] + bv) : 0.f;
      ushort h = f2bf(val);
      Ch[(size_t)m * DKP + n] = h;
      Cl[(size_t)m * DKP + n] = f2bf(val - bf2f(h));
    }
  }
}

// ---- V projection: 64m x 256n per block (n-grid=3). Out Vt[b][d][s] bf16 ----
__global__ __launch_bounds__(256, 4)
void gemm_v(const float* __restrict__ A, const ushort* __restrict__ Bw,
            const float* __restrict__ bias, ushort* __restrict__ Vt)
{
  const int m0 = blockIdx.x * 64;
  const int n0 = blockIdx.y * 256;
  const int tid = threadIdx.x;
  const int w  = tid >> 6;
  const int l  = tid & 63;
  const int lr = l & 15;
  const int lh = l >> 4;

  const f32x4 fzero = {0.f, 0.f, 0.f, 0.f};
  f32x4 acc[16];
#pragma unroll
  for (int nt = 0; nt < 16; ++nt) acc[nt] = fzero;

  const float* arow = A + (size_t)(m0 + w * 16 + lr) * DD + lh * 8;
  const ushort* b0 = Bw + (size_t)(n0 + lr) * DD + lh * 8;

  for (int k = 0; k < DD; k += 32) {
    bf16x8 af = cvt8(arow + k);
#pragma unroll
    for (int nt = 0; nt < 16; ++nt) {
      bf16x8 bfr = *(const bf16x8*)(b0 + (size_t)nt * 16 * DD + k);
      acc[nt] = __builtin_amdgcn_mfma_f32_16x16x32_bf16(af, bfr, acc[nt], 0, 0, 0);
    }
  }

  __shared__ ushort lt[256][72];
#pragma unroll
  for (int nt = 0; nt < 16; ++nt) {
    int nl = nt * 16 + lr;
    float bv = bias[n0 + nl];
#pragma unroll
    for (int r = 0; r < 4; ++r)
      lt[nl][w * 16 + lh * 4 + r] = f2bf(acc[nt][r] + bv);
  }
  __syncthreads();
  const int bb = m0 >> 11;
  const int s0 = m0 & 2047;
  for (int i = tid; i < 256 * 64; i += 256) {
    int nn = i >> 6, mm = i & 63;
    Vt[(size_t)bb * (DD * SS) + (size_t)(n0 + nn) * SS + (s0 + mm)] = lt[nn][mm];
  }
}

// ---- fused attention ----
// Block = (batch via XCD-affine map, 32 q-rows). 8 waves. t-tiles of 64.
// Wave w: S quadrant rows (w&1)*16.., cols (w>>1)*16..; PV d-slice w*96..
// lgkm-only barriers; P/part double-buffered (2 barriers per iter).
// NO register batching (spill-free: ~64 VGPR + ~60 AGPR under the 128 cap).
__global__ __launch_bounds__(512, 4)
void attn_fused(const ushort* __restrict__ Qh, const ushort* __restrict__ Ql,
                const ushort* __restrict__ Kh, const ushort* __restrict__ Kl,
                const ushort* __restrict__ Vt, const float* __restrict__ isc,
                const float* __restrict__ dmask, float* __restrict__ out)
{
  const int bb = blockIdx.x & 7;          // batch <-> XCD affinity (8 XCDs)
  const int q0 = (blockIdx.x >> 3) << 5;
  const int tid = threadIdx.x;
  const int w  = tid >> 6;
  const int l  = tid & 63;
  const int lr = l & 15;
  const int lh = l >> 4;
  const int rh = w & 1;
  const int cq = w >> 1;

  __shared__ __align__(16) ushort Qlh[32][232];
  __shared__ __align__(16) ushort Qll[32][232];
  __shared__ __align__(16) ushort Plds[2][2048];
  __shared__ float part_max[2][4][32];
  __shared__ float part_sum[2][4][32];
  __shared__ float alpha_l[2][32];
  __shared__ float rcpZ[32];

  {
    const size_t qoff = (size_t)(bb * SS + q0) * DKP;
    for (int i = tid; i < 32 * 28; i += 512) {
      int r = i / 28, c = i % 28;
      *(bf16x8*)(&Qlh[r][c * 8]) = *(const bf16x8*)(Qh + qoff + r * DKP + c * 8);
      *(bf16x8*)(&Qll[r][c * 8]) = *(const bf16x8*)(Ql + qoff + r * DKP + c * 8);
    }
  }
  __syncthreads();

  const f32x4 fzero = {0.f, 0.f, 0.f, 0.f};
  float m_run[4], Z_run[4];
#pragma unroll
  for (int r = 0; r < 4; ++r) { m_run[r] = -1e30f; Z_run[r] = 0.f; }
  f32x4 Oacc[2][6];
#pragma unroll
  for (int mt = 0; mt < 2; ++mt)
#pragma unroll
    for (int dt = 0; dt < 6; ++dt) Oacc[mt][dt] = fzero;

  const int qrow_w = rh * 16 + lh * 4;

  const ushort* krh = Kh + (size_t)(bb * SS + cq * 16 + lr) * DKP + lh * 8;
  const ushort* krl = Kl + (size_t)(bb * SS + cq * 16 + lr) * DKP + lh * 8;
  const float*  dmp = dmask + (size_t)bb * SS * SS + (size_t)(q0 + qrow_w) * SS + cq * 16 + lr;
  const float*  icp = isc + (size_t)(q0 + qrow_w) * SS + cq * 16 + lr;
  const ushort* vcr = Vt + (size_t)bb * (DD * SS) + (size_t)(w * 96 + lr) * SS + lh * 8;

  for (int it = 0; it < SS / 64; ++it) {
    const int b = it & 1;
    // current-tile scalar streams early (dmask is the cold HBM stream)
    float dmv[4], icv[4];
#pragma unroll
    for (int r = 0; r < 4; ++r) { dmv[r] = dmp[(size_t)r * SS]; icv[r] = icp[(size_t)r * SS]; }
    // ---- QK: inline K loads, 3 independent accumulator chains ----
    f32x4 a0 = fzero, a1 = fzero, a2 = fzero;
    __builtin_amdgcn_s_setprio(1);
#pragma unroll
    for (int k = 0; k < 7; ++k) {
      bf16x8 kh = *(const bf16x8*)(krh + k * 32);
      bf16x8 kl = *(const bf16x8*)(krl + k * 32);
      bf16x8 ah = *(const bf16x8*)(&Qlh[rh * 16 + lr][k * 32 + lh * 8]);
      bf16x8 al = *(const bf16x8*)(&Qll[rh * 16 + lr][k * 32 + lh * 8]);
      a0 = __builtin_amdgcn_mfma_f32_16x16x32_bf16(ah, kh, a0, 0, 0, 0);
      a1 = __builtin_amdgcn_mfma_f32_16x16x32_bf16(ah, kl, a1, 0, 0, 0);
      a2 = __builtin_amdgcn_mfma_f32_16x16x32_bf16(al, kh, a2, 0, 0, 0);
    }
    __builtin_amdgcn_s_setprio(0);
    f32x4 sacc = (a0 + a1) + a2;
    float sv[4];
#pragma unroll
    for (int r = 0; r < 4; ++r) sv[r] = sacc[r] * __builtin_amdgcn_rcpf(icv[r]);
    // row max over the 16-lane groups
    float mx[4];
#pragma unroll
    for (int r = 0; r < 4; ++r) mx[r] = sv[r];
#pragma unroll
    for (int off = 1; off < 16; off <<= 1) {
#pragma unroll
      for (int r = 0; r < 4; ++r) mx[r] = fmaxf(mx[r], __shfl_xor(mx[r], off));
    }
    if (lr == 0) {
#pragma unroll
      for (int r = 0; r < 4; ++r) part_max[b][cq][qrow_w + r] = mx[r];
    }
    asm volatile("s_waitcnt lgkmcnt(0)" ::: "memory");
    __builtin_amdgcn_s_barrier();                     // barrier A
    float alpha[4], e[4], zl[4];
#pragma unroll
    for (int r = 0; r < 4; ++r) {
      int row = qrow_w + r;
      float mt4 = fmaxf(fmaxf(part_max[b][0][row], part_max[b][1][row]),
                        fmaxf(part_max[b][2][row], part_max[b][3][row]));
      float mnew = fmaxf(m_run[r], mt4);
      alpha[r] = __expf(m_run[r] - mnew);
      m_run[r] = mnew;
      e[r]  = __expf(sv[r] - mnew);
      zl[r] = e[r];
    }
#pragma unroll
    for (int off = 1; off < 16; off <<= 1) {
#pragma unroll
      for (int r = 0; r < 4; ++r) zl[r] += __shfl_xor(zl[r], off);
    }
    if (lr == 0) {
#pragma unroll
      for (int r = 0; r < 4; ++r) part_sum[b][cq][qrow_w + r] = zl[r];
      if (cq == 0) {
#pragma unroll
        for (int r = 0; r < 4; ++r) alpha_l[b][qrow_w + r] = alpha[r];
      }
    }
#pragma unroll
    for (int r = 0; r < 4; ++r) {
      int row = qrow_w + r;
      int col = cq * 16 + lr;
      unsigned off = (unsigned)(row * 128 + col * 2) ^ (((unsigned)row & 7u) << 4);
      *(ushort*)((char*)&Plds[b][0] + off) = f2bf(e[r] * dmv[r]);
    }
    asm volatile("s_waitcnt lgkmcnt(0)" ::: "memory");
    __builtin_amdgcn_s_barrier();                     // barrier B
#pragma unroll
    for (int r = 0; r < 4; ++r) {
      int row = qrow_w + r;
      Z_run[r] = Z_run[r] * alpha[r] +
                 part_sum[b][0][row] + part_sum[b][1][row] +
                 part_sum[b][2][row] + part_sum[b][3][row];
    }
    float oal[2][4]; int need = 0;
#pragma unroll
    for (int mt = 0; mt < 2; ++mt) {
#pragma unroll
      for (int r = 0; r < 4; ++r) {
        float a = alpha_l[b][mt * 16 + lh * 4 + r];
        oal[mt][r] = a;
        need |= (a != 1.f);
      }
    }
    if (__any(need)) {
#pragma unroll
      for (int mt = 0; mt < 2; ++mt)
#pragma unroll
        for (int dt = 0; dt < 6; ++dt)
#pragma unroll
          for (int r = 0; r < 4; ++r) Oacc[mt][dt][r] *= oal[mt][r];
    }
    // ---- PV: P frags from swizzled LDS, V inline (compiler-scheduled) ----
    bf16x8 pf[2][2];
#pragma unroll
    for (int mt = 0; mt < 2; ++mt) {
#pragma unroll
      for (int ks = 0; ks < 2; ++ks) {
        int row = mt * 16 + lr;
        unsigned off = (unsigned)(row * 128 + ks * 64 + lh * 16) ^ (((unsigned)row & 7u) << 4);
        pf[mt][ks] = *(const bf16x8*)((char*)&Plds[b][0] + off);
      }
    }
    __builtin_amdgcn_s_setprio(1);
#pragma unroll
    for (int dt = 0; dt < 6; ++dt) {
#pragma unroll
      for (int ks = 0; ks < 2; ++ks) {
        bf16x8 vf = *(const bf16x8*)(vcr + (size_t)dt * 16 * SS + ks * 32);
        Oacc[0][dt] = __builtin_amdgcn_mfma_f32_16x16x32_bf16(pf[0][ks], vf, Oacc[0][dt], 0, 0, 0);
        Oacc[1][dt] = __builtin_amdgcn_mfma_f32_16x16x32_bf16(pf[1][ks], vf, Oacc[1][dt], 0, 0, 0);
      }
    }
    __builtin_amdgcn_s_setprio(0);
    krh += 64 * DKP; krl += 64 * DKP; dmp += 64; icp += 64; vcr += 64;
  }

  if (w < 2 && lr == 0) {
#pragma unroll
    for (int r = 0; r < 4; ++r) rcpZ[qrow_w + r] = 1.0f / Z_run[r];
  }
  __syncthreads();

  float* obase = out + (size_t)(bb * SS + q0) * DD + w * 96;
#pragma unroll
  for (int mt = 0; mt < 2; ++mt) {
#pragma unroll
    for (int dt = 0; dt < 6; ++dt) {
#pragma unroll
      for (int r = 0; r < 4; ++r) {
        int row = mt * 16 + lh * 4 + r;
        obase[(size_t)row * DD + dt * 16 + lr] = Oacc[mt][dt][r] * rcpZ[row];
      }
    }
  }
}

extern "C" void kernel_launch(void* const* d_in, const int* in_sizes, int n_in,
                              void* d_out, int out_size, void* d_ws, size_t ws_size,
                              hipStream_t stream) {
  const float* x1  = (const float*)d_in[0];
  const float* x2  = (const float*)d_in[1];
  const float* x3  = (const float*)d_in[2];
  const float* Wq  = (const float*)d_in[3];
  const float* bq  = (const float*)d_in[4];
  const float* Wk  = (const float*)d_in[5];
  const float* bk  = (const float*)d_in[6];
  const float* Wv  = (const float*)d_in[7];
  const float* bv  = (const float*)d_in[8];
  const float* isc = (const float*)d_in[9];
  const float* dmk = (const float*)d_in[10];
  float* out = (float*)d_out;

  const size_t QK = (size_t)16384 * DKP;
  const size_t WN = (size_t)WROWS * DD;
  ushort* Qh  = (ushort*)d_ws;
  ushort* Ql  = Qh + QK;
  ushort* Kh  = Ql + QK;
  ushort* Kl  = Kh + QK;
  ushort* Vt  = Kl + QK;                       // [8][768][2048]
  ushort* Wqh = Vt + (size_t)NB * DD * SS;
  ushort* Wql = Wqh + WN;
  ushort* Wkh = Wql + WN;
  ushort* Wkl = Wkh + WN;
  ushort* Wvb = Wkl + WN;                      // [768][768]

  dim3 blk(256);
  prep_w<<<dim3(512), blk, 0, stream>>>(Wq, Wk, Wv, Wqh, Wql, Wkh, Wkl, Wvb);
  gemm_qk<<<dim3(256), blk, 0, stream>>>(x1, Wqh, Wql, bq, Qh, Ql);
  gemm_qk<<<dim3(256), blk, 0, stream>>>(x2, Wkh, Wkl, bk, Kh, Kl);
  gemm_v <<<dim3(256, 3), blk, 0, stream>>>(x3, Wvb, bv, Vt);
  attn_fused<<<dim3(512), dim3(512), 0, stream>>>(Qh, Ql, Kh, Kl, Vt, isc, dmk, out);
}

// Round 6
// 555.682 us; speedup vs baseline: 2.1303x; 1.4812x over previous
//
#include <hip/hip_runtime.h>
#include <hip/hip_bf16.h>

typedef unsigned short ushort;
typedef short bf16x8 __attribute__((ext_vector_type(8)));
typedef float f32x4 __attribute__((ext_vector_type(4)));

#define NB 8
#define SS 2048
#define DD 768
#define DKV 214
#define DKP 224
#define WROWS 256

__device__ __forceinline__ float bf2f(ushort u) {
  union { unsigned int i; float f; } v; v.i = ((unsigned int)u) << 16; return v.f;
}
__device__ __forceinline__ ushort f2bf(float f) {
  union { float f; unsigned int i; } v; v.f = f;
  unsigned int x = v.i;
  return (ushort)((x + 0x7fffu + ((x >> 16) & 1u)) >> 16);
}
__device__ __forceinline__ bf16x8 cvt8(const float* p) {
  f32x4 a = *(const f32x4*)p;
  f32x4 b = *(const f32x4*)(p + 4);
  bf16x8 r;
#pragma unroll
  for (int j = 0; j < 4; ++j) { r[j] = (short)f2bf(a[j]); r[j + 4] = (short)f2bf(b[j]); }
  return r;
}
__device__ __forceinline__ void split8(const float* p, bf16x8& h, bf16x8& l) {
  f32x4 a = *(const f32x4*)p;
  f32x4 b = *(const f32x4*)(p + 4);
#pragma unroll
  for (int j = 0; j < 4; ++j) {
    ushort h0 = f2bf(a[j]); h[j]     = (short)h0; l[j]     = (short)f2bf(a[j] - bf2f(h0));
    ushort h1 = f2bf(b[j]); h[j + 4] = (short)h1; l[j + 4] = (short)f2bf(b[j] - bf2f(h1));
  }
}

// ---- weight prep: split Wq,Wk -> k-packed [24][256][32] hi/lo (rows>=DKV zeroed);
//      cvt Wv -> k-packed [24][768][32] bf16.
// k-packed layout makes every MFMA B-fragment a contiguous 1KB wave-load.
__global__ __launch_bounds__(256)
void prep_w(const float* __restrict__ Wq, const float* __restrict__ Wk,
            const float* __restrict__ Wv,
            ushort* __restrict__ Wqh, ushort* __restrict__ Wql,
            ushort* __restrict__ Wkh, ushort* __restrict__ Wkl,
            ushort* __restrict__ Wvb)
{
  const int NW = WROWS * DD;
  const int NV = DD * DD;
  for (int i = blockIdx.x * 256 + threadIdx.x; i < 2 * NW + NV; i += gridDim.x * 256) {
    if (i < NW) {
      int r = i / DD, c = i % DD;
      float v = (r < DKV) ? Wq[i] : 0.f;
      ushort h = f2bf(v);
      int d = (c >> 5) * (WROWS * 32) + r * 32 + (c & 31);
      Wqh[d] = h; Wql[d] = f2bf(v - bf2f(h));
    } else if (i < 2 * NW) {
      int j = i - NW;
      int r = j / DD, c = j % DD;
      float v = (r < DKV) ? Wk[j] : 0.f;
      ushort h = f2bf(v);
      int d = (c >> 5) * (WROWS * 32) + r * 32 + (c & 31);
      Wkh[d] = h; Wkl[d] = f2bf(v - bf2f(h));
    } else {
      int j = i - 2 * NW;
      int r = j / DD, c = j % DD;
      Wvb[(c >> 5) * (DD * 32) + r * 32 + (c & 31)] = f2bf(Wv[j]);
    }
  }
}

// ---- fused Q+K projection. Grid (256, 4): y>>1 selects {Q,K}, y&1 = n-half.
// Tile 64m x 128n, 4 waves (wave = 16m x 128n, acc[8] = 32 AGPR).
// A: direct f32 + in-reg split. B: k-packed slabs, contiguous 1KB frag loads.
__global__ __launch_bounds__(256, 4)
void gemm_qk(const float* __restrict__ x1, const float* __restrict__ x2,
             const ushort* __restrict__ Wqh, const ushort* __restrict__ Wql,
             const ushort* __restrict__ Wkh, const ushort* __restrict__ Wkl,
             const float* __restrict__ bq, const float* __restrict__ bk,
             ushort* __restrict__ Qh, ushort* __restrict__ Ql,
             ushort* __restrict__ Kh, ushort* __restrict__ Kl)
{
  const int m0 = blockIdx.x * 64;
  const int which = blockIdx.y >> 1;
  const int n0 = (blockIdx.y & 1) * 128;
  const int tid = threadIdx.x;
  const int w  = tid >> 6;
  const int l  = tid & 63;
  const int lr = l & 15;
  const int lh = l >> 4;

  const float*  A    = which ? x2 : x1;
  const ushort* Bh   = which ? Wkh : Wqh;
  const ushort* Bl   = which ? Wkl : Wql;
  const float*  bias = which ? bk : bq;
  ushort* Ch = which ? Kh : Qh;
  ushort* Cl = which ? Kl : Ql;

  const f32x4 fzero = {0.f, 0.f, 0.f, 0.f};
  f32x4 acc[8];
#pragma unroll
  for (int nt = 0; nt < 8; ++nt) acc[nt] = fzero;

  const float* arow = A + (size_t)(m0 + w * 16 + lr) * DD + lh * 8;
  const int boff = (n0 + lr) * 32 + lh * 8;   // within a [256][32] k-slab

  for (int kk = 0; kk < 24; ++kk) {
    bf16x8 ah, al; split8(arow + kk * 32, ah, al);
    const ushort* bhp = Bh + kk * (WROWS * 32) + boff;
    const ushort* blp = Bl + kk * (WROWS * 32) + boff;
#pragma unroll
    for (int nt = 0; nt < 8; ++nt) {
      bf16x8 wh = *(const bf16x8*)(bhp + nt * 512);
      bf16x8 wl = *(const bf16x8*)(blp + nt * 512);
      acc[nt] = __builtin_amdgcn_mfma_f32_16x16x32_bf16(ah, wh, acc[nt], 0, 0, 0);
      acc[nt] = __builtin_amdgcn_mfma_f32_16x16x32_bf16(ah, wl, acc[nt], 0, 0, 0);
      acc[nt] = __builtin_amdgcn_mfma_f32_16x16x32_bf16(al, wh, acc[nt], 0, 0, 0);
    }
  }

#pragma unroll
  for (int nt = 0; nt < 8; ++nt) {
    int n = n0 + nt * 16 + lr;
    if (n >= DKP) continue;
    float bv = (n < DKV) ? bias[n] : 0.f;
#pragma unroll
    for (int r = 0; r < 4; ++r) {
      int m = m0 + w * 16 + lh * 4 + r;
      float val = (n < DKV) ? (acc[nt][r] + bv) : 0.f;
      ushort h = f2bf(val);
      Ch[(size_t)m * DKP + n] = h;
      Cl[(size_t)m * DKP + n] = f2bf(val - bf2f(h));
    }
  }
}

// ---- V projection: tile 64m x 256n, grid (256,3). B k-packed. Out Vt[b][d][s] ----
__global__ __launch_bounds__(256, 3)
void gemm_v(const float* __restrict__ A, const ushort* __restrict__ Bw,
            const float* __restrict__ bias, ushort* __restrict__ Vt)
{
  const int m0 = blockIdx.x * 64;
  const int n0 = blockIdx.y * 256;
  const int tid = threadIdx.x;
  const int w  = tid >> 6;
  const int l  = tid & 63;
  const int lr = l & 15;
  const int lh = l >> 4;

  const f32x4 fzero = {0.f, 0.f, 0.f, 0.f};
  f32x4 acc[16];
#pragma unroll
  for (int nt = 0; nt < 16; ++nt) acc[nt] = fzero;

  const float* arow = A + (size_t)(m0 + w * 16 + lr) * DD + lh * 8;
  const int boff = (n0 + lr) * 32 + lh * 8;   // within a [768][32] k-slab

  for (int kk = 0; kk < 24; ++kk) {
    bf16x8 af = cvt8(arow + kk * 32);
    const ushort* bp = Bw + kk * (DD * 32) + boff;
#pragma unroll
    for (int nt = 0; nt < 16; ++nt) {
      bf16x8 bfr = *(const bf16x8*)(bp + nt * 512);
      acc[nt] = __builtin_amdgcn_mfma_f32_16x16x32_bf16(af, bfr, acc[nt], 0, 0, 0);
    }
  }

  __shared__ ushort lt[256][72];
#pragma unroll
  for (int nt = 0; nt < 16; ++nt) {
    int nl = nt * 16 + lr;
    float bv = bias[n0 + nl];
#pragma unroll
    for (int r = 0; r < 4; ++r)
      lt[nl][w * 16 + lh * 4 + r] = f2bf(acc[nt][r] + bv);
  }
  __syncthreads();
  const int bb = m0 >> 11;
  const int s0 = m0 & 2047;
  for (int i = tid; i < 256 * 64; i += 256) {
    int nn = i >> 6, mm = i & 63;
    Vt[(size_t)bb * (DD * SS) + (size_t)(n0 + nn) * SS + (s0 + mm)] = lt[nn][mm];
  }
}

// ---- fused attention (R5 structure + next-iter inv_scale prefetch) ----
__global__ __launch_bounds__(512, 4)
void attn_fused(const ushort* __restrict__ Qh, const ushort* __restrict__ Ql,
                const ushort* __restrict__ Kh, const ushort* __restrict__ Kl,
                const ushort* __restrict__ Vt, const float* __restrict__ isc,
                const float* __restrict__ dmask, float* __restrict__ out)
{
  const int bb = blockIdx.x & 7;          // batch <-> XCD affinity
  const int q0 = (blockIdx.x >> 3) << 5;
  const int tid = threadIdx.x;
  const int w  = tid >> 6;
  const int l  = tid & 63;
  const int lr = l & 15;
  const int lh = l >> 4;
  const int rh = w & 1;
  const int cq = w >> 1;

  __shared__ __align__(16) ushort Qlh[32][232];
  __shared__ __align__(16) ushort Qll[32][232];
  __shared__ __align__(16) ushort Plds[2][2048];
  __shared__ float part_max[2][4][32];
  __shared__ float part_sum[2][4][32];
  __shared__ float alpha_l[2][32];
  __shared__ float rcpZ[32];

  {
    const size_t qoff = (size_t)(bb * SS + q0) * DKP;
    for (int i = tid; i < 32 * 28; i += 512) {
      int r = i / 28, c = i % 28;
      *(bf16x8*)(&Qlh[r][c * 8]) = *(const bf16x8*)(Qh + qoff + r * DKP + c * 8);
      *(bf16x8*)(&Qll[r][c * 8]) = *(const bf16x8*)(Ql + qoff + r * DKP + c * 8);
    }
  }
  __syncthreads();

  const f32x4 fzero = {0.f, 0.f, 0.f, 0.f};
  float m_run[4], Z_run[4];
#pragma unroll
  for (int r = 0; r < 4; ++r) { m_run[r] = -1e30f; Z_run[r] = 0.f; }
  f32x4 Oacc[2][6];
#pragma unroll
  for (int mt = 0; mt < 2; ++mt)
#pragma unroll
    for (int dt = 0; dt < 6; ++dt) Oacc[mt][dt] = fzero;

  const int qrow_w = rh * 16 + lh * 4;

  const ushort* krh = Kh + (size_t)(bb * SS + cq * 16 + lr) * DKP + lh * 8;
  const ushort* krl = Kl + (size_t)(bb * SS + cq * 16 + lr) * DKP + lh * 8;
  const float*  dmp = dmask + (size_t)bb * SS * SS + (size_t)(q0 + qrow_w) * SS + cq * 16 + lr;
  const float*  icp = isc + (size_t)(q0 + qrow_w) * SS + cq * 16 + lr;
  const ushort* vcr = Vt + (size_t)bb * (DD * SS) + (size_t)(w * 96 + lr) * SS + lh * 8;

  // preload tile-0 inv_scale; icp then points at the NEXT tile
  float icv[4];
#pragma unroll
  for (int r = 0; r < 4; ++r) icv[r] = icp[(size_t)r * SS];
  icp += 64;

  for (int it = 0; it < SS / 64; ++it) {
    const int b = it & 1;
    const bool more = (it + 1 < SS / 64);
    // current-tile dropout mask early (cold HBM stream; consumed at P-write)
    float dmv[4];
#pragma unroll
    for (int r = 0; r < 4; ++r) dmv[r] = dmp[(size_t)r * SS];
    // ---- QK: inline K loads, 3 independent accumulator chains ----
    f32x4 a0 = fzero, a1 = fzero, a2 = fzero;
    __builtin_amdgcn_s_setprio(1);
#pragma unroll
    for (int k = 0; k < 7; ++k) {
      bf16x8 kh = *(const bf16x8*)(krh + k * 32);
      bf16x8 kl = *(const bf16x8*)(krl + k * 32);
      bf16x8 ah = *(const bf16x8*)(&Qlh[rh * 16 + lr][k * 32 + lh * 8]);
      bf16x8 al = *(const bf16x8*)(&Qll[rh * 16 + lr][k * 32 + lh * 8]);
      a0 = __builtin_amdgcn_mfma_f32_16x16x32_bf16(ah, kh, a0, 0, 0, 0);
      a1 = __builtin_amdgcn_mfma_f32_16x16x32_bf16(ah, kl, a1, 0, 0, 0);
      a2 = __builtin_amdgcn_mfma_f32_16x16x32_bf16(al, kh, a2, 0, 0, 0);
    }
    __builtin_amdgcn_s_setprio(0);
    // prefetch NEXT tile's inv_scale (consumed right after next QK)
    float icn[4];
    if (more) {
#pragma unroll
      for (int r = 0; r < 4; ++r) icn[r] = icp[(size_t)r * SS];
    }
    f32x4 sacc = (a0 + a1) + a2;
    float sv[4];
#pragma unroll
    for (int r = 0; r < 4; ++r) sv[r] = sacc[r] * __builtin_amdgcn_rcpf(icv[r]);
    // row max over the 16-lane groups
    float mx[4];
#pragma unroll
    for (int r = 0; r < 4; ++r) mx[r] = sv[r];
#pragma unroll
    for (int off = 1; off < 16; off <<= 1) {
#pragma unroll
      for (int r = 0; r < 4; ++r) mx[r] = fmaxf(mx[r], __shfl_xor(mx[r], off));
    }
    if (lr == 0) {
#pragma unroll
      for (int r = 0; r < 4; ++r) part_max[b][cq][qrow_w + r] = mx[r];
    }
    asm volatile("s_waitcnt lgkmcnt(0)" ::: "memory");
    __builtin_amdgcn_s_barrier();                     // barrier A
    float alpha[4], e[4], zl[4];
#pragma unroll
    for (int r = 0; r < 4; ++r) {
      int row = qrow_w + r;
      float mt4 = fmaxf(fmaxf(part_max[b][0][row], part_max[b][1][row]),
                        fmaxf(part_max[b][2][row], part_max[b][3][row]));
      float mnew = fmaxf(m_run[r], mt4);
      alpha[r] = __expf(m_run[r] - mnew);
      m_run[r] = mnew;
      e[r]  = __expf(sv[r] - mnew);
      zl[r] = e[r];
    }
#pragma unroll
    for (int off = 1; off < 16; off <<= 1) {
#pragma unroll
      for (int r = 0; r < 4; ++r) zl[r] += __shfl_xor(zl[r], off);
    }
    if (lr == 0) {
#pragma unroll
      for (int r = 0; r < 4; ++r) part_sum[b][cq][qrow_w + r] = zl[r];
      if (cq == 0) {
#pragma unroll
        for (int r = 0; r < 4; ++r) alpha_l[b][qrow_w + r] = alpha[r];
      }
    }
#pragma unroll
    for (int r = 0; r < 4; ++r) {
      int row = qrow_w + r;
      int col = cq * 16 + lr;
      unsigned off = (unsigned)(row * 128 + col * 2) ^ (((unsigned)row & 7u) << 4);
      *(ushort*)((char*)&Plds[b][0] + off) = f2bf(e[r] * dmv[r]);
    }
    asm volatile("s_waitcnt lgkmcnt(0)" ::: "memory");
    __builtin_amdgcn_s_barrier();                     // barrier B
#pragma unroll
    for (int r = 0; r < 4; ++r) {
      int row = qrow_w + r;
      Z_run[r] = Z_run[r] * alpha[r] +
                 part_sum[b][0][row] + part_sum[b][1][row] +
                 part_sum[b][2][row] + part_sum[b][3][row];
    }
    float oal[2][4]; int need = 0;
#pragma unroll
    for (int mt = 0; mt < 2; ++mt) {
#pragma unroll
      for (int r = 0; r < 4; ++r) {
        float a = alpha_l[b][mt * 16 + lh * 4 + r];
        oal[mt][r] = a;
        need |= (a != 1.f);
      }
    }
    if (__any(need)) {
#pragma unroll
      for (int mt = 0; mt < 2; ++mt)
#pragma unroll
        for (int dt = 0; dt < 6; ++dt)
#pragma unroll
          for (int r = 0; r < 4; ++r) Oacc[mt][dt][r] *= oal[mt][r];
    }
    // ---- PV ----
    bf16x8 pf[2][2];
#pragma unroll
    for (int mt = 0; mt < 2; ++mt) {
#pragma unroll
      for (int ks = 0; ks < 2; ++ks) {
        int row = mt * 16 + lr;
        unsigned off = (unsigned)(row * 128 + ks * 64 + lh * 16) ^ (((unsigned)row & 7u) << 4);
        pf[mt][ks] = *(const bf16x8*)((char*)&Plds[b][0] + off);
      }
    }
    __builtin_amdgcn_s_setprio(1);
#pragma unroll
    for (int dt = 0; dt < 6; ++dt) {
#pragma unroll
      for (int ks = 0; ks < 2; ++ks) {
        bf16x8 vf = *(const bf16x8*)(vcr + (size_t)dt * 16 * SS + ks * 32);
        Oacc[0][dt] = __builtin_amdgcn_mfma_f32_16x16x32_bf16(pf[0][ks], vf, Oacc[0][dt], 0, 0, 0);
        Oacc[1][dt] = __builtin_amdgcn_mfma_f32_16x16x32_bf16(pf[1][ks], vf, Oacc[1][dt], 0, 0, 0);
      }
    }
    __builtin_amdgcn_s_setprio(0);
    if (more) {
#pragma unroll
      for (int r = 0; r < 4; ++r) icv[r] = icn[r];
    }
    krh += 64 * DKP; krl += 64 * DKP; dmp += 64; icp += 64; vcr += 64;
  }

  if (w < 2 && lr == 0) {
#pragma unroll
    for (int r = 0; r < 4; ++r) rcpZ[qrow_w + r] = 1.0f / Z_run[r];
  }
  __syncthreads();

  float* obase = out + (size_t)(bb * SS + q0) * DD + w * 96;
#pragma unroll
  for (int mt = 0; mt < 2; ++mt) {
#pragma unroll
    for (int dt = 0; dt < 6; ++dt) {
#pragma unroll
      for (int r = 0; r < 4; ++r) {
        int row = mt * 16 + lh * 4 + r;
        obase[(size_t)row * DD + dt * 16 + lr] = Oacc[mt][dt][r] * rcpZ[row];
      }
    }
  }
}

extern "C" void kernel_launch(void* const* d_in, const int* in_sizes, int n_in,
                              void* d_out, int out_size, void* d_ws, size_t ws_size,
                              hipStream_t stream) {
  const float* x1  = (const float*)d_in[0];
  const float* x2  = (const float*)d_in[1];
  const float* x3  = (const float*)d_in[2];
  const float* Wq  = (const float*)d_in[3];
  const float* bq  = (const float*)d_in[4];
  const float* Wk  = (const float*)d_in[5];
  const float* bk  = (const float*)d_in[6];
  const float* Wv  = (const float*)d_in[7];
  const float* bv  = (const float*)d_in[8];
  const float* isc = (const float*)d_in[9];
  const float* dmk = (const float*)d_in[10];
  float* out = (float*)d_out;

  const size_t QK = (size_t)16384 * DKP;
  const size_t WN = (size_t)WROWS * DD;
  ushort* Qh  = (ushort*)d_ws;
  ushort* Ql  = Qh + QK;
  ushort* Kh  = Ql + QK;
  ushort* Kl  = Kh + QK;
  ushort* Vt  = Kl + QK;                       // [8][768][2048]
  ushort* Wqh = Vt + (size_t)NB * DD * SS;     // k-packed [24][256][32]
  ushort* Wql = Wqh + WN;
  ushort* Wkh = Wql + WN;
  ushort* Wkl = Wkh + WN;
  ushort* Wvb = Wkl + WN;                      // k-packed [24][768][32]

  dim3 blk(256);
  prep_w<<<dim3(512), blk, 0, stream>>>(Wq, Wk, Wv, Wqh, Wql, Wkh, Wkl, Wvb);
  gemm_qk<<<dim3(256, 4), blk, 0, stream>>>(x1, x2, Wqh, Wql, Wkh, Wkl, bq, bk,
                                            Qh, Ql, Kh, Kl);
  gemm_v <<<dim3(256, 3), blk, 0, stream>>>(x3, Wvb, bv, Vt);
  attn_fused<<<dim3(512), dim3(512), 0, stream>>>(Qh, Ql, Kh, Kl, Vt, isc, dmk, out);
}